// Round 5
// baseline (44.771 us; speedup 1.0000x reference)
//
#include <hip/hip_runtime.h>
#include <hip/hip_bf16.h>
#include <cstdint>

#define LL 256   // L
#define NN 512   // N
#define DD 256   // D
#define HH 8
#define EPSF 1e-5f
#define WGS 264  // WgL row stride, bf16 elems (528 B -> 2-way-free LDS reads)
#define TS  264  // msa tile row stride, bf16 elems (528 B)

typedef __attribute__((ext_vector_type(8))) __bf16 bf16x8;
typedef __attribute__((ext_vector_type(4))) __bf16 bf16x4;
typedef __attribute__((ext_vector_type(4))) float f32x4;

static __device__ __forceinline__ void lb_sync() {
    // barrier WITHOUT vmcnt drain: publish LDS (lgkm) only; global loads stay in flight
    __builtin_amdgcn_sched_barrier(0);
    asm volatile("s_waitcnt lgkmcnt(0)" ::: "memory");
    __builtin_amdgcn_s_barrier();
    __builtin_amdgcn_sched_barrier(0);
}

static __device__ __forceinline__ void loadg(
    const float* __restrict__ msa, int l, int wave, int lane, int t, float4 (&buf)[16])
{
    // one instruction = one full 1KB row (64 lanes x 16B contiguous)
    #pragma unroll
    for (int r = 0; r < 16; ++r)
        buf[r] = *((const float4*)(msa + ((size_t)(t * 128 + wave * 16 + r) * LL + l) * DD) + lane);
}

static __device__ __forceinline__ void dswcvt(
    const float4 (&buf)[16], __bf16* tile, int wave, int lane)
{
    #pragma unroll
    for (int r = 0; r < 16; ++r) {
        float4 u = buf[r];
        bf16x4 b;
        b[0] = (__bf16)u.x; b[1] = (__bf16)u.y; b[2] = (__bf16)u.z; b[3] = (__bf16)u.w;
        *(bf16x4*)(tile + (wave * 16 + r) * TS + lane * 4) = b;
    }
}

static __device__ __forceinline__ void compute_t(
    int g, const __bf16* tile, const bf16x8 (&bfr)[8], int wave, int col, int kb,
    float* logits, float* sS, float* sQ)
{
    f32x4 ha = {0.f, 0.f, 0.f, 0.f}, ga = {0.f, 0.f, 0.f, 0.f};
    const __bf16* arow = tile + (wave * 16 + col) * TS;
    #pragma unroll
    for (int ks = 0; ks < 8; ++ks) {
        bf16x8 a = *(const bf16x8*)(arow + ks * 32 + kb * 8);
        ha = __builtin_amdgcn_mfma_f32_16x16x32_bf16(a, bfr[ks], ha, 0, 0, 0);
        ga = __builtin_amdgcn_mfma_f32_16x16x32_bf16(a, a,       ga, 0, 0, 0);
    }
    const int nb = g * 128 + wave * 16;
    #pragma unroll
    for (int i = 0; i < 4; ++i) {
        int n = nb + (kb << 2) + i;          // C/D: col=lane&15, row=kb*4+i
        if (col < HH)       logits[col * NN + n] = ha[i];
        else if (col == HH) sS[n] = ha[i];
    }
    if (kb == (col >> 2)) sQ[nb + col] = ga[col & 3];   // Gram diagonal = Σx̂²
}

__global__ __launch_bounds__(512, 2) void k_fused(
    const float* __restrict__ msa, const float* __restrict__ Wq,
    const float* __restrict__ bq, const float* __restrict__ Wk,
    const float* __restrict__ gamma, const float* __restrict__ beta,
    float* __restrict__ out)
{
    const int l = blockIdx.x;
    const int tid = threadIdx.x, wave = tid >> 6, lane = tid & 63;
    const int col = lane & 15, kb = lane >> 4;

    __shared__ __align__(16) __bf16 tile[128 * TS];   // 67.6 KB bf16 staging tile
    __shared__ __align__(16) __bf16 WgL[16 * WGS];    // 8.4 KB fused weights
    __shared__ __align__(16) float logits[HH * NN];   // 16 KB
    __shared__ __align__(16) float sS[NN];            // Σx̂
    __shared__ __align__(16) float sQ[NN];            // Σx̂²
    __shared__ float lnx[DD];
    __shared__ float qv[DD];
    __shared__ float red[8];
    __shared__ float stats[16];
    __shared__ float Gs[HH];

    // ---- prefetch tiles 0 and 1 (latency hides under phase 1) ----
    float4 P[16], Q[16];
    loadg(msa, l, wave, lane, 0, P);
    loadg(msa, l, wave, lane, 1, Q);

    // ---------- Phase 1: Wg = gamma ⊙ (q·Wk) in LDS ----------
    {
        float x0 = (tid < DD) ? msa[(size_t)l * DD + tid] : 0.f;
        float s = x0, ss = x0 * x0;
        #pragma unroll
        for (int m = 32; m >= 1; m >>= 1) { s += __shfl_xor(s, m); ss += __shfl_xor(ss, m); }
        if (tid < DD && lane == 0) { red[wave * 2] = s; red[wave * 2 + 1] = ss; }
        lb_sync();
        if (tid < DD) {
            float sm = red[0] + red[2] + red[4] + red[6];
            float sq = red[1] + red[3] + red[5] + red[7];
            float mean = sm * (1.f / DD);
            float var  = sq * (1.f / DD) - mean * mean;
            float rs   = rsqrtf(var + EPSF);
            lnx[tid] = (x0 - mean) * rs * gamma[tid] + beta[tid];
        }
        lb_sync();
        const int r = tid & 255, hf = tid >> 8;
        float acc = 0.f;
        {
            const float4* wr = (const float4*)(Wq + (size_t)r * DD) + hf * 32;
            const float* lx = lnx + hf * 128;
            #pragma unroll 4
            for (int j = 0; j < 32; ++j) {
                float4 w4 = wr[j];
                acc += lx[4*j] * w4.x + lx[4*j+1] * w4.y + lx[4*j+2] * w4.z + lx[4*j+3] * w4.w;
            }
        }
        if (hf == 0) qv[r] = acc;
        lb_sync();
        if (hf == 1) qv[r] = (qv[r] + acc + bq[r]) * 0.17677669529663687f;
        lb_sync();
        const int c = tid & 255, h0 = (tid >> 8) * 4;
        const float gm = gamma[c];
        #pragma unroll
        for (int hi = 0; hi < 4; ++hi) {
            int h = h0 + hi;
            float a = 0.f;
            const float* wk = Wk + ((size_t)h * 32) * DD + c;
            #pragma unroll 8
            for (int d = 0; d < 32; ++d)
                a += qv[h * 32 + d] * wk[(size_t)d * DD];
            WgL[h * WGS + c] = (__bf16)(gm * a);
        }
        if (tid < DD) {
            WgL[8 * WGS + tid] = (__bf16)1.0f;       // ones column -> row sums
        } else {
            const int c2 = tid - 256;
            #pragma unroll
            for (int h = 9; h < 16; ++h) WgL[h * WGS + c2] = (__bf16)0.0f;
        }
        lb_sync();
        if (wave < HH) {                             // G[h] = Σ_c Wg[h][c]
            float gsum = 0.f;
            #pragma unroll
            for (int i = 0; i < 4; ++i) gsum += (float)WgL[wave * WGS + lane * 4 + i];
            #pragma unroll
            for (int m = 32; m >= 1; m >>= 1) gsum += __shfl_xor(gsum, m);
            if (lane == 0) Gs[wave] = gsum;
        }
        lb_sync();
    }

    // ---------- B fragments ----------
    bf16x8 bfr[8];
    #pragma unroll
    for (int ks = 0; ks < 8; ++ks)
        bfr[ks] = *(const bf16x8*)&WgL[col * WGS + ks * 32 + kb * 8];

    // ---------- Main loop: 4 tiles of 128 rows, staged bf16, 2-deep pipeline ----------
    dswcvt(P, tile, wave, lane);  loadg(msa, l, wave, lane, 2, P);  lb_sync();
    compute_t(0, tile, bfr, wave, col, kb, logits, sS, sQ);         lb_sync();
    dswcvt(Q, tile, wave, lane);  loadg(msa, l, wave, lane, 3, Q);  lb_sync();
    compute_t(1, tile, bfr, wave, col, kb, logits, sS, sQ);         lb_sync();
    dswcvt(P, tile, wave, lane);                                    lb_sync();
    compute_t(2, tile, bfr, wave, col, kb, logits, sS, sQ);         lb_sync();
    dswcvt(Q, tile, wave, lane);                                    lb_sync();
    compute_t(3, tile, bfr, wave, col, kb, logits, sS, sQ);         lb_sync();

    // ---------- softmax stats: wave w -> head h=w ----------
    {
        const int h = wave;
        const float Gh = Gs[h];
        const float* lp = logits + h * NN;
        float4 ra = ((const float4*)lp)[lane * 2];
        float4 rb = ((const float4*)lp)[lane * 2 + 1];
        float4 sa = ((const float4*)sS)[lane * 2];
        float4 sb = ((const float4*)sS)[lane * 2 + 1];
        float4 qa = ((const float4*)sQ)[lane * 2];
        float4 qb = ((const float4*)sQ)[lane * 2 + 1];
        float raw[8] = {ra.x, ra.y, ra.z, ra.w, rb.x, rb.y, rb.z, rb.w};
        float sv[8]  = {sa.x, sa.y, sa.z, sa.w, sb.x, sb.y, sb.z, sb.w};
        float qv2[8] = {qa.x, qa.y, qa.z, qa.w, qb.x, qb.y, qb.z, qb.w};
        float adj[8];
        #pragma unroll
        for (int i = 0; i < 8; ++i) {
            float mean = sv[i] * (1.f / DD);
            float var  = qv2[i] * (1.f / DD) - mean * mean;
            float rs   = rsqrtf(var + EPSF);
            adj[i] = rs * (raw[i] - mean * Gh);
        }
        float mx = adj[0];
        #pragma unroll
        for (int i = 1; i < 8; ++i) mx = fmaxf(mx, adj[i]);
        #pragma unroll
        for (int m = 32; m >= 1; m >>= 1) mx = fmaxf(mx, __shfl_xor(mx, m));
        float sm = 0.f;
        #pragma unroll
        for (int i = 0; i < 8; ++i) sm += __expf(adj[i] - mx);
        #pragma unroll
        for (int m = 32; m >= 1; m >>= 1) sm += __shfl_xor(sm, m);
        if (lane == 0) { stats[wave] = mx; stats[8 + wave] = 1.f / sm; }
    }
    lb_sync();

    // ---------- epilogue: thread t -> n=t, 8 heads, fp32 out ----------
    {
        const int n = tid;
        float s = sS[n], q2 = sQ[n];
        float mean = s * (1.f / DD);
        float var  = q2 * (1.f / DD) - mean * mean;
        float rs   = rsqrtf(var + EPSF);
        float o[8];
        #pragma unroll
        for (int h = 0; h < HH; ++h) {
            float adj = rs * (logits[h * NN + n] - mean * Gs[h]);
            o[h] = __expf(adj - stats[h]) * stats[8 + h];
        }
        float* op = out + (size_t)n * LL * HH + (size_t)l * HH;
        float4 p0 = {o[0], o[1], o[2], o[3]};
        float4 p1 = {o[4], o[5], o[6], o[7]};
        *(float4*)(op)     = p0;
        *(float4*)(op + 4) = p1;
    }
}

extern "C" void kernel_launch(void* const* d_in, const int* in_sizes, int n_in,
                              void* d_out, int out_size, void* d_ws, size_t ws_size,
                              hipStream_t stream) {
    (void)in_sizes; (void)n_in; (void)out_size; (void)d_ws; (void)ws_size;
    const float* msa   = (const float*)d_in[0];
    const float* Wq    = (const float*)d_in[1];
    const float* bq    = (const float*)d_in[2];
    const float* Wk    = (const float*)d_in[3];
    // d_in[4] = bk: per-(l,h) constant in logits -> cancelled by softmax over n.
    const float* gamma = (const float*)d_in[5];
    const float* beta  = (const float*)d_in[6];
    k_fused<<<dim3(LL), dim3(512), 0, stream>>>(msa, Wq, bq, Wk, gamma, beta, (float*)d_out);
}